// Round 7
// baseline (181.477 us; speedup 1.0000x reference)
//
#include <hip/hip_runtime.h>

// SimpleRetention on MI355X (gfx950), bf16 MFMA path.
// ret = (S * sigmoid(S)) @ V,  S = (Q K^T) * gamma^|n-m|
// B=8, S=2048, H=512, gamma = 31/32. Decay band truncated at +-256..319.
//
// v6: proj 2-phase double-buffer (T3 minimum recipe). Round-6 arithmetic:
// proj ran ~105us vs ~11us pipe floors because each K-step's stage was
// drained by the very next barrier (full L2 latency exposed x8). Now:
// stage(k0+64)->buf^1 issued BEFORE compute(buf), ONE barrier/iter ->
// stage latency hides under 32 MFMA + next ds_reads. attn unchanged (60us).

typedef short  bf16x8 __attribute__((ext_vector_type(8)));
typedef float  f32x4  __attribute__((ext_vector_type(4)));

constexpr int S_LEN = 2048;
constexpr int HID   = 512;
constexpr int BAND  = 256;

#define GAMMA_L2 (-0.045803689613125f)   /* log2(31/32) */
#define LOG2E    (1.4426950408889634f)

__device__ __forceinline__ ushort f2bf(float f) {
  union { float f; unsigned u; } v; v.f = f;
  unsigned u = v.u;
  u += 0x7FFFu + ((u >> 16) & 1u);      // RNE, matches v_cvt
  return (ushort)(u >> 16);
}

__device__ __forceinline__ void gld_lds16(const ushort* g, ushort* l) {
  __builtin_amdgcn_global_load_lds(
      (const __attribute__((address_space(1))) void*)g,
      (__attribute__((address_space(3))) void*)l, 16, 0, 0);
}

// ---------------------------------------------------------------- cvt X -> bf16
__global__ void cvt_x_kernel(const float* __restrict__ X, ushort* __restrict__ Xb) {
  const int n4 = (8 * S_LEN * HID) / 4;
  int i = blockIdx.x * blockDim.x + threadIdx.x;
  const int stride = gridDim.x * blockDim.x;
  for (; i < n4; i += stride) {
    float4 v = ((const float4*)X)[i];
    ushort4 o;
    o.x = f2bf(v.x); o.y = f2bf(v.y); o.z = f2bf(v.z); o.w = f2bf(v.w);
    ((ushort4*)Xb)[i] = o;
  }
}

// ------------------------------------------------ cvt + transpose W -> Wt bf16
__global__ void cvt_w_kernel(const float* __restrict__ Wq, const float* __restrict__ Wk,
                             const float* __restrict__ Wv, ushort* __restrict__ Wtb) {
  __shared__ float tile[64][65];
  const int mat = blockIdx.z;
  const float* Wm = (mat == 0) ? Wq : ((mat == 1) ? Wk : Wv);
  const int k0 = blockIdx.y * 64, n0 = blockIdx.x * 64;
  const int t = threadIdx.x;
  const int c = t & 63, r0 = t >> 6;
  #pragma unroll
  for (int i = 0; i < 16; i++) {
    const int r = i * 4 + r0;
    tile[r][c] = Wm[(size_t)(k0 + r) * HID + n0 + c];
  }
  __syncthreads();
  ushort* Wt = Wtb + (size_t)mat * HID * HID;
  #pragma unroll
  for (int i = 0; i < 16; i++) {
    const int r = i * 4 + r0;
    Wt[(size_t)(n0 + r) * HID + k0 + c] = f2bf(tile[c][r]);
  }
}

// -------------------------------------------------------------- projection GEMM
// C = Xb @ W  (M=16384, N=512, K=512), 3 mats. 128x128 tile, BK=64, 4 waves,
// each wave 64x64 (4x4 of 16x16x32). 2-PHASE DOUBLE-BUFFER: stage(k0+64) into
// buf^1 issued before compute(buf); one barrier/iter (drains prefetch vmcnt +
// WAR-safe: reads of buf finished at the same barrier). global_load_lds(16B)
// with XOR slot-swizzle (both-sides, rule 21) -> conflict-free ds_read_b128.
// XCD-locality: xcd = bid&7 owns a contiguous 2048-row X slice + all W -> L2.
// Outputs fragment-linear:
//   Q2/K2: addr(r,h) = (r>>4)*8192 + (h>>3)*128 + (r&15)*8 + (h&7)
//   V2 per batch: b*1048576 + (h>>4)*32768 + (s>>3)*128 + (h&15)*8 + (s&7)
__global__ void __launch_bounds__(256) proj_kernel(
    const ushort* __restrict__ Xb, const ushort* __restrict__ Wtb,
    ushort* __restrict__ Qb, ushort* __restrict__ Kb, ushort* __restrict__ Vtb) {
  __shared__ __align__(16) ushort lsA[2][128 * 64];   // 32KB
  __shared__ __align__(16) ushort lsB[2][128 * 64];   // 32KB
  const int bid  = blockIdx.x;
  const int xcd  = bid & 7;
  const int idx  = bid >> 3;
  const int rsub = idx / 12;
  const int cm   = idx - rsub * 12;
  const int mat  = cm >> 2;
  const int C0   = (cm & 3) * 128;
  const int R0   = (xcd * 16 + rsub) * 128;
  const int tid = threadIdx.x;
  const int w = tid >> 6, l = tid & 63;
  const int hl = l >> 4, l15 = l & 15;
  const int wr = w >> 1, wc = w & 1;
  const ushort* Wm = Wtb + (size_t)mat * HID * HID;

  const int srow = l >> 3;
  const int scol = ((l & 7) ^ srow) * 8;

  f32x4 acc[4][4] = {};

  // stage: instr i covers LDS rows [i*8,i*8+8); source slot pre-swizzled
  #define STAGE_P(K0, BUF)                                                  \
    { _Pragma("unroll")                                                     \
      for (int j = 0; j < 4; j++) {                                         \
        const int i = w * 4 + j;                                            \
        const int r = i * 8 + srow;                                         \
        gld_lds16(Xb + (size_t)(R0 + r) * HID + (K0) + scol,                \
                  lsA[BUF] + i * 512);                                      \
        gld_lds16(Wm + (size_t)(C0 + r) * HID + (K0) + scol,                \
                  lsB[BUF] + i * 512);                                      \
      } }

  STAGE_P(0, 0);
  __syncthreads();                       // prologue drain

  #pragma unroll
  for (int it = 0; it < 8; it++) {       // k0 = it*64; cur = it&1 (static)
    const int cur = it & 1;
    if (it < 7) STAGE_P((it + 1) * 64, cur ^ 1);   // prefetch flies over MFMA
    #pragma unroll
    for (int kf = 0; kf < 2; kf++) {
      bf16x8 af[4], bfr[4];
      #pragma unroll
      for (int mi = 0; mi < 4; mi++) {
        const int r  = wr * 64 + mi * 16 + l15;
        const int sl = ((kf * 4 + hl) ^ (r & 7)) * 8;
        af[mi] = *(const bf16x8*)(lsA[cur] + r * 64 + sl);
      }
      #pragma unroll
      for (int nj = 0; nj < 4; nj++) {
        const int r  = wc * 64 + nj * 16 + l15;
        const int sl = ((kf * 4 + hl) ^ (r & 7)) * 8;
        bfr[nj] = *(const bf16x8*)(lsB[cur] + r * 64 + sl);
      }
      #pragma unroll
      for (int mi = 0; mi < 4; mi++)
        #pragma unroll
        for (int nj = 0; nj < 4; nj++)
          acc[mi][nj] = __builtin_amdgcn_mfma_f32_16x16x32_bf16(
              af[mi], bfr[nj], acc[mi][nj], 0, 0, 0);
    }
    __syncthreads();   // drains prefetch (vmcnt0) + all waves done with cur
  }

  if (mat < 2) {
    ushort* Op = (mat == 0) ? Qb : Kb;
    #pragma unroll
    for (int mi = 0; mi < 4; mi++) {
      const int r16 = R0 + wr * 64 + mi * 16;
      const size_t sb = ((size_t)r16 >> 4) * 8192;
      #pragma unroll
      for (int nj = 0; nj < 4; nj++) {
        const int h = C0 + wc * 64 + nj * 16 + l15;
        const size_t ha = sb + (size_t)(h >> 3) * 128 + (h & 7);
        #pragma unroll
        for (int i = 0; i < 4; i++)
          Op[ha + (hl * 4 + i) * 8] = f2bf(acc[mi][nj][i]);
      }
    }
  } else {
    const int b = R0 >> 11;
    ushort* Vt = Vtb + (size_t)b * 1048576;
    #pragma unroll
    for (int mi = 0; mi < 4; mi++) {
      const int sb16 = (R0 & 2047) + wr * 64 + mi * 16;
      const size_t sa = (size_t)((sb16 >> 3) + (hl >> 1)) * 128 + (hl & 1) * 4;
      #pragma unroll
      for (int nj = 0; nj < 4; nj++) {
        const int hv = (C0 + wc * 64) / 16 + nj;
        ushort4 pk;
        pk.x = f2bf(acc[mi][nj][0]); pk.y = f2bf(acc[mi][nj][1]);
        pk.z = f2bf(acc[mi][nj][2]); pk.w = f2bf(acc[mi][nj][3]);
        *(ushort4*)(Vt + (size_t)hv * 32768 + sa + l15 * 8) = pk;
      }
    }
  }
}

// ------------------------------------------------------------- fused retention
// (unchanged from round 6 — 60us, passing.)
// Block = 16 q-rows, 4 waves, KVBLK=64. Wave w: QK for kv rows [16w,16w+16)
// (K A-frags direct from frag-linear K2, Q B-frags from LDS), swish, write P
// quarter to shared LDS; barrier; PV for h-quarter (full P via conflict-free
// ds_read_b128, V direct from L2) -> accO[8]. 1024 blocks x 4 waves;
// b = bid&7 pins batch -> XCD (per-batch K2+V2 = 4MB = its L2).
__global__ void __launch_bounds__(256, 4) attn_kernel(
    const ushort* __restrict__ Q2, const ushort* __restrict__ K2,
    const ushort* __restrict__ V2, float* __restrict__ Out) {
  __shared__ __align__(16) ushort Qlds[16 * 512];     // 16KB, = Q2 block copy
  __shared__ __align__(16) ushort Pb[2][16 * 72];     // 4.5KB dbuf, 144B rows
  const int b = blockIdx.x & 7, q0 = (blockIdx.x >> 3) * 16;
  const int tid = threadIdx.x;
  const int w = tid >> 6, l = tid & 63;
  const int hl = l >> 4, l15 = l & 15;

  const ushort* Qg = Q2 + ((size_t)(b * 128 + (q0 >> 4))) * 8192;
  #pragma unroll
  for (int j = 0; j < 4; j++) {
    const int kf = w * 4 + j;
    gld_lds16(Qg + kf * 512 + l * 8, Qlds + kf * 512);
  }

  f32x4 accO[8] = {};
  const int t_lo = (q0 - BAND) < 0 ? 0 : ((q0 - BAND) >> 6);
  int t_hi = ((q0 + 15 + BAND) >> 6) + 1;
  if (t_hi > S_LEN / 64) t_hi = S_LEN / 64;

  const float qrow = (float)(q0 + l15);
  const int bK = b * 128;
  const ushort* Vb = V2 + (size_t)b * 1048576 + (size_t)w * 8 * 32768
                        + hl * 128 + l15 * 8;

  #define QK_T(T, STV)                                                       \
    {                                                                        \
      const ushort* Kt = K2 + ((size_t)(bK + (T) * 4 + w)) * 8192 + l * 8;   \
      _Pragma("unroll")                                                      \
      for (int kf = 0; kf < 16; kf++) {                                      \
        bf16x8 kfr = *(const bf16x8*)(Kt + kf * 512);                        \
        bf16x8 qfr = *(const bf16x8*)(Qlds + kf * 512 + l * 8);              \
        STV = __builtin_amdgcn_mfma_f32_16x16x32_bf16(kfr, qfr, STV, 0, 0, 0); \
      }                                                                      \
    }

  #define SWISH_P(T, STV, BUF)                                               \
    {                                                                        \
      ushort4 pk;                                                            \
      _Pragma("unroll")                                                      \
      for (int i = 0; i < 4; i++) {                                          \
        const float kvf = (float)((T) * 64 + w * 16 + hl * 4 + i);           \
        const float ad = fabsf(kvf - qrow);                                  \
        const float s = STV[i] * exp2f(GAMMA_L2 * ad);                       \
        const float p = s * __builtin_amdgcn_rcpf(1.0f + exp2f(-LOG2E * s)); \
        ((ushort*)&pk)[i] = f2bf(p);                                         \
      }                                                                      \
      *(ushort4*)(Pb[BUF] + l15 * 72 + w * 16 + hl * 4) = pk;                \
    }

  #define PV_T(T, BUF)                                                       \
    {                                                                        \
      bf16x8 pa0 = *(const bf16x8*)(Pb[BUF] + l15 * 72 + hl * 8);            \
      bf16x8 pa1 = *(const bf16x8*)(Pb[BUF] + l15 * 72 + 32 + hl * 8);       \
      const ushort* Vt = Vb + (size_t)(T) * 1024;                            \
      _Pragma("unroll")                                                      \
      for (int nfi = 0; nfi < 8; nfi++) {                                    \
        bf16x8 v0 = *(const bf16x8*)(Vt + (size_t)nfi * 32768);              \
        bf16x8 v1 = *(const bf16x8*)(Vt + (size_t)nfi * 32768 + 512);        \
        accO[nfi] = __builtin_amdgcn_mfma_f32_16x16x32_bf16(pa0, v0, accO[nfi], 0, 0, 0); \
        accO[nfi] = __builtin_amdgcn_mfma_f32_16x16x32_bf16(pa1, v1, accO[nfi], 0, 0, 0); \
      }                                                                      \
    }

  __syncthreads();                       // Q staged (barrier drains vmcnt)

  {
    f32x4 st = {};
    QK_T(t_lo, st);
    SWISH_P(t_lo, st, t_lo & 1);
  }
  __syncthreads();

  for (int t = t_lo; t < t_hi; ++t) {
    PV_T(t, t & 1);
    if (t + 1 < t_hi) {
      f32x4 st = {};
      QK_T(t + 1, st);
      SWISH_P(t + 1, st, (t + 1) & 1);
    }
    __syncthreads();
  }

  float* Ob = Out + ((size_t)b * S_LEN + q0) * HID + w * 128;
  #pragma unroll
  for (int nfi = 0; nfi < 8; nfi++)
    #pragma unroll
    for (int i = 0; i < 4; i++)
      Ob[(size_t)(hl * 4 + i) * HID + nfi * 16 + l15] = accO[nfi][i];
}

// ---------------------------------------------------------------------- launch
extern "C" void kernel_launch(void* const* d_in, const int* in_sizes, int n_in,
                              void* d_out, int out_size, void* d_ws, size_t ws_size,
                              hipStream_t stream) {
  const float* X  = (const float*)d_in[0];
  const float* Wq = (const float*)d_in[1];
  const float* Wk = (const float*)d_in[2];
  const float* Wv = (const float*)d_in[3];
  float* Out = (float*)d_out;

  char* ws = (char*)d_ws;
  ushort* Xb  = (ushort*)(ws);                      // 16 MiB  bf16 X
  ushort* Wtb = (ushort*)(ws + 16777216);           // 1.5 MiB bf16 W^T x3
  ushort* Qb  = (ushort*)(ws + 18350080);           // 16 MiB (frag-linear Q2)
  ushort* Kb  = (ushort*)(ws + 35127296);           // 16 MiB (frag-linear K2)
  ushort* Vtb = (ushort*)(ws + 51904512);           // 16 MiB (frag-linear V2)

  cvt_x_kernel<<<2048, 256, 0, stream>>>(X, Xb);
  cvt_w_kernel<<<dim3(8, 8, 3), 256, 0, stream>>>(Wq, Wk, Wv, Wtb);
  proj_kernel<<<1536, 256, 0, stream>>>(Xb, Wtb, Qb, Kb, Vtb);
  attn_kernel<<<1024, 256, 0, stream>>>(Qb, Kb, Vtb, Out);
}

// Round 8
// 172.036 us; speedup vs baseline: 1.0549x; 1.0549x over previous
//
#include <hip/hip_runtime.h>

// SimpleRetention on MI355X (gfx950), bf16 MFMA path.
// ret = (S * sigmoid(S)) @ V,  S = (Q K^T) * gamma^|n-m|
// B=8, S=2048, H=512, gamma = 31/32. Decay band truncated at +-256..319.
//
// v7: (a) proj: 8-wave blocks (512 thr) with the 2-phase dbuf -> 16 waves/CU
// (round-7 dbuf had halved co-residency to 8 waves/CU: pipelining gain ==
// occupancy loss, net 0). (b) attn: 2-deep pipeline (PV(t),PV(t+1) ||
// QK(t+2),QK(t+3) per barrier region, P quad-buffered -> barriers 9->5) and
// QK dep-chain split 16->2x8. Layouts/swish/traffic identical to round 6.

typedef short  bf16x8 __attribute__((ext_vector_type(8)));
typedef float  f32x4  __attribute__((ext_vector_type(4)));

constexpr int S_LEN = 2048;
constexpr int HID   = 512;
constexpr int BAND  = 256;

#define GAMMA_L2 (-0.045803689613125f)   /* log2(31/32) */
#define LOG2E    (1.4426950408889634f)

__device__ __forceinline__ ushort f2bf(float f) {
  union { float f; unsigned u; } v; v.f = f;
  unsigned u = v.u;
  u += 0x7FFFu + ((u >> 16) & 1u);      // RNE, matches v_cvt
  return (ushort)(u >> 16);
}

__device__ __forceinline__ void gld_lds16(const ushort* g, ushort* l) {
  __builtin_amdgcn_global_load_lds(
      (const __attribute__((address_space(1))) void*)g,
      (__attribute__((address_space(3))) void*)l, 16, 0, 0);
}

// ---------------------------------------------------------------- cvt X -> bf16
__global__ void cvt_x_kernel(const float* __restrict__ X, ushort* __restrict__ Xb) {
  const int n4 = (8 * S_LEN * HID) / 4;
  int i = blockIdx.x * blockDim.x + threadIdx.x;
  const int stride = gridDim.x * blockDim.x;
  for (; i < n4; i += stride) {
    float4 v = ((const float4*)X)[i];
    ushort4 o;
    o.x = f2bf(v.x); o.y = f2bf(v.y); o.z = f2bf(v.z); o.w = f2bf(v.w);
    ((ushort4*)Xb)[i] = o;
  }
}

// ------------------------------------------------ cvt + transpose W -> Wt bf16
__global__ void cvt_w_kernel(const float* __restrict__ Wq, const float* __restrict__ Wk,
                             const float* __restrict__ Wv, ushort* __restrict__ Wtb) {
  __shared__ float tile[64][65];
  const int mat = blockIdx.z;
  const float* Wm = (mat == 0) ? Wq : ((mat == 1) ? Wk : Wv);
  const int k0 = blockIdx.y * 64, n0 = blockIdx.x * 64;
  const int t = threadIdx.x;
  const int c = t & 63, r0 = t >> 6;
  #pragma unroll
  for (int i = 0; i < 16; i++) {
    const int r = i * 4 + r0;
    tile[r][c] = Wm[(size_t)(k0 + r) * HID + n0 + c];
  }
  __syncthreads();
  ushort* Wt = Wtb + (size_t)mat * HID * HID;
  #pragma unroll
  for (int i = 0; i < 16; i++) {
    const int r = i * 4 + r0;
    Wt[(size_t)(n0 + r) * HID + k0 + c] = f2bf(tile[c][r]);
  }
}

// -------------------------------------------------------------- projection GEMM
// C = Xb @ W  (M=16384, N=512, K=512), 3 mats. 128x128 tile, BK=64, 8 waves
// (wave tile 64x32: acc 4x2 f32x4 = 32 VGPR). 2-phase dbuf: stage(k0+64) into
// buf^1 before compute(buf), one barrier/iter. 64KB LDS -> 2 blocks/CU x 8
// waves = 16 waves/CU. XOR slot-swizzle both-sides (rule 21), conflict-free
// ds_read_b128. XCD-locality: xcd = bid&7 owns a 2048-row X slice + all W.
// Outputs fragment-linear:
//   Q2/K2: addr(r,h) = (r>>4)*8192 + (h>>3)*128 + (r&15)*8 + (h&7)
//   V2 per batch: b*1048576 + (h>>4)*32768 + (s>>3)*128 + (h&15)*8 + (s&7)
__global__ void __launch_bounds__(512, 4) proj_kernel(
    const ushort* __restrict__ Xb, const ushort* __restrict__ Wtb,
    ushort* __restrict__ Qb, ushort* __restrict__ Kb, ushort* __restrict__ Vtb) {
  __shared__ __align__(16) ushort lsA[2][128 * 64];   // 32KB
  __shared__ __align__(16) ushort lsB[2][128 * 64];   // 32KB
  const int bid  = blockIdx.x;
  const int xcd  = bid & 7;
  const int idx  = bid >> 3;
  const int rsub = idx / 12;
  const int cm   = idx - rsub * 12;
  const int mat  = cm >> 2;
  const int C0   = (cm & 3) * 128;
  const int R0   = (xcd * 16 + rsub) * 128;
  const int tid = threadIdx.x;
  const int w = tid >> 6, l = tid & 63;
  const int hl = l >> 4, l15 = l & 15;
  const int wr = w >> 2, wc = w & 3;         // wave tile 64 rows x 32 cols
  const ushort* Wm = Wtb + (size_t)mat * HID * HID;

  const int srow = l >> 3;
  const int scol = ((l & 7) ^ srow) * 8;

  f32x4 acc[4][2] = {};

  // stage: instr i covers LDS rows [i*8,i*8+8); source slot pre-swizzled
  #define STAGE_P(K0, BUF)                                                  \
    { _Pragma("unroll")                                                     \
      for (int j = 0; j < 2; j++) {                                         \
        const int i = w * 2 + j;                                            \
        const int r = i * 8 + srow;                                         \
        gld_lds16(Xb + (size_t)(R0 + r) * HID + (K0) + scol,                \
                  lsA[BUF] + i * 512);                                      \
        gld_lds16(Wm + (size_t)(C0 + r) * HID + (K0) + scol,                \
                  lsB[BUF] + i * 512);                                      \
      } }

  STAGE_P(0, 0);
  __syncthreads();                       // prologue drain

  #pragma unroll
  for (int it = 0; it < 8; it++) {       // k0 = it*64; cur = it&1 (static)
    const int cur = it & 1;
    if (it < 7) STAGE_P((it + 1) * 64, cur ^ 1);   // prefetch flies over MFMA
    #pragma unroll
    for (int kf = 0; kf < 2; kf++) {
      bf16x8 af[4], bfr[2];
      #pragma unroll
      for (int mi = 0; mi < 4; mi++) {
        const int r  = wr * 64 + mi * 16 + l15;
        const int sl = ((kf * 4 + hl) ^ (r & 7)) * 8;
        af[mi] = *(const bf16x8*)(lsA[cur] + r * 64 + sl);
      }
      #pragma unroll
      for (int nj = 0; nj < 2; nj++) {
        const int r  = wc * 32 + nj * 16 + l15;
        const int sl = ((kf * 4 + hl) ^ (r & 7)) * 8;
        bfr[nj] = *(const bf16x8*)(lsB[cur] + r * 64 + sl);
      }
      #pragma unroll
      for (int mi = 0; mi < 4; mi++)
        #pragma unroll
        for (int nj = 0; nj < 2; nj++)
          acc[mi][nj] = __builtin_amdgcn_mfma_f32_16x16x32_bf16(
              af[mi], bfr[nj], acc[mi][nj], 0, 0, 0);
    }
    __syncthreads();   // drains prefetch + all waves done with cur
  }

  if (mat < 2) {
    ushort* Op = (mat == 0) ? Qb : Kb;
    #pragma unroll
    for (int mi = 0; mi < 4; mi++) {
      const int r16 = R0 + wr * 64 + mi * 16;
      const size_t sb = ((size_t)r16 >> 4) * 8192;
      #pragma unroll
      for (int nj = 0; nj < 2; nj++) {
        const int h = C0 + wc * 32 + nj * 16 + l15;
        const size_t ha = sb + (size_t)(h >> 3) * 128 + (h & 7);
        #pragma unroll
        for (int i = 0; i < 4; i++)
          Op[ha + (hl * 4 + i) * 8] = f2bf(acc[mi][nj][i]);
      }
    }
  } else {
    const int b = R0 >> 11;
    ushort* Vt = Vtb + (size_t)b * 1048576;
    #pragma unroll
    for (int mi = 0; mi < 4; mi++) {
      const int sb16 = (R0 & 2047) + wr * 64 + mi * 16;
      const size_t sa = (size_t)((sb16 >> 3) + (hl >> 1)) * 128 + (hl & 1) * 4;
      #pragma unroll
      for (int nj = 0; nj < 2; nj++) {
        const int hv = (C0 + wc * 32) / 16 + nj;
        ushort4 pk;
        pk.x = f2bf(acc[mi][nj][0]); pk.y = f2bf(acc[mi][nj][1]);
        pk.z = f2bf(acc[mi][nj][2]); pk.w = f2bf(acc[mi][nj][3]);
        *(ushort4*)(Vt + (size_t)hv * 32768 + sa + l15 * 8) = pk;
      }
    }
  }
}

// ------------------------------------------------------------- fused retention
// Block = 16 q-rows, 4 waves, KVBLK=64, 2-DEEP pipeline: per barrier region
// {PV(t), PV(t+1) || QK(t+2)->P, QK(t+3)->P}, P quad-buffered (Pb[t&3]).
// QK split into two 8-deep MFMA chains (halves dep-chain latency). Wave w:
// QK kv rows [16w,16w+16), PV h-quarter [128w,128w+128) -> accO[8].
// 1024 blocks x 4 waves; b = bid&7 pins batch -> XCD (K2+V2 = 4MB = its L2).
__global__ void __launch_bounds__(256, 4) attn_kernel(
    const ushort* __restrict__ Q2, const ushort* __restrict__ K2,
    const ushort* __restrict__ V2, float* __restrict__ Out) {
  __shared__ __align__(16) ushort Qlds[16 * 512];     // 16KB, = Q2 block copy
  __shared__ __align__(16) ushort Pb[4][16 * 72];     // 9KB quad-buf, 144B rows
  const int b = blockIdx.x & 7, q0 = (blockIdx.x >> 3) * 16;
  const int tid = threadIdx.x;
  const int w = tid >> 6, l = tid & 63;
  const int hl = l >> 4, l15 = l & 15;

  const ushort* Qg = Q2 + ((size_t)(b * 128 + (q0 >> 4))) * 8192;
  #pragma unroll
  for (int j = 0; j < 4; j++) {
    const int kf = w * 4 + j;
    gld_lds16(Qg + kf * 512 + l * 8, Qlds + kf * 512);
  }

  f32x4 accO[8] = {};
  const int t_lo = (q0 - BAND) < 0 ? 0 : ((q0 - BAND) >> 6);
  int t_hi = ((q0 + 15 + BAND) >> 6) + 1;
  if (t_hi > S_LEN / 64) t_hi = S_LEN / 64;

  const float qrow = (float)(q0 + l15);
  const int bK = b * 128;
  const ushort* Vb = V2 + (size_t)b * 1048576 + (size_t)w * 8 * 32768
                        + hl * 128 + l15 * 8;

  // QK quarter, dep-chain split 2x8: S^T[kv 16w..16w+16][q 16]
  #define QK_T2(T, S0, S1)                                                   \
    {                                                                        \
      const ushort* Kt = K2 + ((size_t)(bK + (T) * 4 + w)) * 8192 + l * 8;   \
      _Pragma("unroll")                                                      \
      for (int kf = 0; kf < 8; kf++) {                                       \
        bf16x8 kfr = *(const bf16x8*)(Kt + kf * 512);                        \
        bf16x8 qfr = *(const bf16x8*)(Qlds + kf * 512 + l * 8);              \
        S0 = __builtin_amdgcn_mfma_f32_16x16x32_bf16(kfr, qfr, S0, 0, 0, 0); \
      }                                                                      \
      _Pragma("unroll")                                                      \
      for (int kf = 8; kf < 16; kf++) {                                      \
        bf16x8 kfr = *(const bf16x8*)(Kt + kf * 512);                        \
        bf16x8 qfr = *(const bf16x8*)(Qlds + kf * 512 + l * 8);              \
        S1 = __builtin_amdgcn_mfma_f32_16x16x32_bf16(kfr, qfr, S1, 0, 0, 0); \
      }                                                                      \
    }

  // decay + swish on S0+S1, pack into Pb[BUF] (rows=q l15, cols=kv)
  #define SWISH_P(T, S0, S1, BUF)                                            \
    {                                                                        \
      ushort4 pk;                                                            \
      _Pragma("unroll")                                                      \
      for (int i = 0; i < 4; i++) {                                          \
        const float kvf = (float)((T) * 64 + w * 16 + hl * 4 + i);           \
        const float ad = fabsf(kvf - qrow);                                  \
        const float sv = (S0[i] + S1[i]) * exp2f(GAMMA_L2 * ad);             \
        const float p = sv * __builtin_amdgcn_rcpf(1.0f + exp2f(-LOG2E * sv)); \
        ((ushort*)&pk)[i] = f2bf(p);                                         \
      }                                                                      \
      *(ushort4*)(Pb[BUF] + l15 * 72 + w * 16 + hl * 4) = pk;                \
    }

  // PV: O[q][hq] += P[q][kv64] * V[kv64][hq]
  #define PV_T(T, BUF)                                                       \
    {                                                                        \
      bf16x8 pa0 = *(const bf16x8*)(Pb[BUF] + l15 * 72 + hl * 8);            \
      bf16x8 pa1 = *(const bf16x8*)(Pb[BUF] + l15 * 72 + 32 + hl * 8);       \
      const ushort* Vt = Vb + (size_t)(T) * 1024;                            \
      _Pragma("unroll")                                                      \
      for (int nfi = 0; nfi < 8; nfi++) {                                    \
        bf16x8 v0 = *(const bf16x8*)(Vt + (size_t)nfi * 32768);              \
        bf16x8 v1 = *(const bf16x8*)(Vt + (size_t)nfi * 32768 + 512);        \
        accO[nfi] = __builtin_amdgcn_mfma_f32_16x16x32_bf16(pa0, v0, accO[nfi], 0, 0, 0); \
        accO[nfi] = __builtin_amdgcn_mfma_f32_16x16x32_bf16(pa1, v1, accO[nfi], 0, 0, 0); \
      }                                                                      \
    }

  __syncthreads();                       // Q staged (barrier drains vmcnt)

  {                                      // prologue: P(t_lo), P(t_lo+1)
    f32x4 s0 = {}, s1 = {};
    QK_T2(t_lo, s0, s1);
    SWISH_P(t_lo, s0, s1, t_lo & 3);
  }
  {
    f32x4 s0 = {}, s1 = {};
    QK_T2(t_lo + 1, s0, s1);
    SWISH_P(t_lo + 1, s0, s1, (t_lo + 1) & 3);
  }
  __syncthreads();

  for (int t = t_lo; t < t_hi; t += 2) {
    PV_T(t, t & 3);
    if (t + 1 < t_hi) PV_T(t + 1, (t + 1) & 3);
    if (t + 2 < t_hi) {
      f32x4 s0 = {}, s1 = {};
      QK_T2(t + 2, s0, s1);
      SWISH_P(t + 2, s0, s1, (t + 2) & 3);
    }
    if (t + 3 < t_hi) {
      f32x4 s0 = {}, s1 = {};
      QK_T2(t + 3, s0, s1);
      SWISH_P(t + 3, s0, s1, (t + 3) & 3);
    }
    __syncthreads();                     // one rendezvous per 2 kv-tiles
  }

  float* Ob = Out + ((size_t)b * S_LEN + q0) * HID + w * 128;
  #pragma unroll
  for (int nfi = 0; nfi < 8; nfi++)
    #pragma unroll
    for (int i = 0; i < 4; i++)
      Ob[(size_t)(hl * 4 + i) * HID + nfi * 16 + l15] = accO[nfi][i];
}

// ---------------------------------------------------------------------- launch
extern "C" void kernel_launch(void* const* d_in, const int* in_sizes, int n_in,
                              void* d_out, int out_size, void* d_ws, size_t ws_size,
                              hipStream_t stream) {
  const float* X  = (const float*)d_in[0];
  const float* Wq = (const float*)d_in[1];
  const float* Wk = (const float*)d_in[2];
  const float* Wv = (const float*)d_in[3];
  float* Out = (float*)d_out;

  char* ws = (char*)d_ws;
  ushort* Xb  = (ushort*)(ws);                      // 16 MiB  bf16 X
  ushort* Wtb = (ushort*)(ws + 16777216);           // 1.5 MiB bf16 W^T x3
  ushort* Qb  = (ushort*)(ws + 18350080);           // 16 MiB (frag-linear Q2)
  ushort* Kb  = (ushort*)(ws + 35127296);           // 16 MiB (frag-linear K2)
  ushort* Vtb = (ushort*)(ws + 51904512);           // 16 MiB (frag-linear V2)

  cvt_x_kernel<<<2048, 256, 0, stream>>>(X, Xb);
  cvt_w_kernel<<<dim3(8, 8, 3), 256, 0, stream>>>(Wq, Wk, Wv, Wtb);
  proj_kernel<<<1536, 512, 0, stream>>>(Xb, Wtb, Qb, Kb, Vtb);
  attn_kernel<<<1024, 256, 0, stream>>>(Qb, Kb, Vtb, Out);
}